// Round 5
// baseline (88.517 us; speedup 1.0000x reference)
//
#include <hip/hip_runtime.h>

// Pipeline_8400956031319: dual greedy NMS (8192 det + 8192 rpn, IOU>0.6,
// index order) + argmax masking.
//
// R16 rev — ONE plain dispatch, manual LLC coherence, zero release fences.
// Evidence: R13 (5 nodes, 79.5) ~= R15 (2 nodes + ticket, 78.2) => dispatch
// boundaries are cheap (~1-3us); the ~35us non-fill residual lives INSIDE
// the kernels. Prime suspect in R15: 512 per-block RELEASE-scope fetch_adds
// (agent release can emit an L2 writeback; 64/XCD serialized = tens of us).
// R14 showed cg::grid.sync is 45us each — also banned. This round removes
// every fence/release and every extra dispatch:
//
//   fused2_kernel, 256 blocks x 512 threads (guaranteed co-resident:
//   1 block/CU min x 256 CUs; LDS 57.5KB -> 2 blocks/CU capacity):
//   A) blocks 0..31 bin partials (block b: set=b>>4, rows (b&15)*512+t,
//      LDS count+prefix, compacted {box words,id} + packed {off,cnt}
//      written as agent-RELAXED u32 atomics straight to LLC), then
//      s_waitcnt vmcnt(0) + per-block DOUBLE-MAGIC flag (two distinct
//      magic words => single-pattern ws poison can never alias => no
//      init dispatch needed).
//   J1) all 256 blocks poll the 32 fA flags (safe: all resident).
//   B) each block runs 2 pair tasks (same cell, det then rpn): gather 3x3
//      neighborhood (<=144 runs, LDS prefix + binary search) via agent
//      loads; identical flattened pair loop + exact ref IOU; edges
//      (i<<13|j, once via orig_a < orig_b) via agent stores. Overflow ->
//      exact full-scan fallback (never taken). vmcnt(0) + fB flag.
//   J2) blocks >=32 exit; blocks 0..31 poll the 256 fB flags, then run
//      the unchanged Jacobi fixpoint (keep[j] = !(exists i<j edge with
//      kept i); unique fixpoint == greedy NMS) + coalesced float4
//      epilogue (magic-div row decode).
//
// Ordering proof: writer does data-astores -> vmcnt(0) retires (all acked
// at LLC) -> THEN issues flag astores. Reader sees flags only after they
// reach LLC, by which time data is in LLC; reader uses agent loads (bypass
// L1/L2) and issues them after the poll loop exits (in-order issue).

constexpr int NROWS = 8192;
constexpr int NKW   = 256;      // keep words (u32) per set
constexpr unsigned BCAP = 1536; // staged 3x3 neighborhood cap (mean ~288)
constexpr unsigned RCAP = 2048; // per-cell edge region cap (mean ~12)
constexpr unsigned ELDS = 12288;// solve LDS edge cache (~4x expected ~3k)
#define IOU_T 0.6f
constexpr unsigned MG1 = 0x4D41474Bu;  // double-magic flag words — poison is
constexpr unsigned MG2 = 0xB17EC0DEu;  // one repeated pattern, can't be both

// ws layout (all cross-block data accessed with agent-scope u32 atomics):
//   [0    ) fA   [32][2] u32    (binner done flags)
//   [1024 ) fB   [256][2] u32   (pair done flags)
//   [4096 ) ecnt [512] u32
//   [8192 ) edges[512][RCAP] u32          (4 MB)
//   [+4MB ) pbw  [32*512][4] u32 box words (1 MB)
//   [+    ) pid  [32*512] u32              (64 KB)
//   [+    ) pofs [32][256] u32 packed off|cnt<<16 (32 KB)
constexpr size_t OFF_FA    = 0;
constexpr size_t OFF_FB    = 1024;
constexpr size_t OFF_ECNT  = 4096;
constexpr size_t OFF_EDGES = 8192;
constexpr size_t OFF_PBW   = OFF_EDGES + (size_t)512 * RCAP * 4;
constexpr size_t OFF_PID   = OFF_PBW   + (size_t)32 * 512 * 16;
constexpr size_t OFF_POFS  = OFF_PID   + (size_t)32 * 512 * 4;

__device__ __forceinline__ unsigned aload(const unsigned* p) {
  return __hip_atomic_load(p, __ATOMIC_RELAXED, __HIP_MEMORY_SCOPE_AGENT);
}
__device__ __forceinline__ void astore(unsigned* p, unsigned v) {
  __hip_atomic_store(p, v, __ATOMIC_RELAXED, __HIP_MEMORY_SCOPE_AGENT);
}

union __align__(16) Smem {
  struct {                       // phase A (binners): 2 KB
    unsigned cnt[256], off[256];
  } a;
  struct {                       // phase B: ~38.2 KB
    float4   B4[BCAP];
    float    Bar[BCAP];
    unsigned Bid[BCAP];
    unsigned runStart[144];
    unsigned runBase[144];
  } p;
  struct {                       // phase S: ~57.3 KB
    unsigned eL[ELDS];
    unsigned rcnt[256], roff[256];
    unsigned kbuf[2][NKW];
    float    vmsk[512], imsk[512];
  } s;
};

__global__ __launch_bounds__(512) void fused2_kernel(
    const float* __restrict__ det, const float* __restrict__ rpn,
    unsigned* __restrict__ fA, unsigned* __restrict__ fB,
    unsigned* __restrict__ ecnt, unsigned* __restrict__ edges,
    unsigned* __restrict__ pbw, unsigned* __restrict__ pid,
    unsigned* __restrict__ pofs, float* __restrict__ out)
{
  __shared__ Smem U;
  __shared__ unsigned ncell[9];
  __shared__ unsigned nN_sh, na_sh, nb_sh, eC, bad, Etot_sh;
  __shared__ int changed[2];

  const int bid = blockIdx.x;
  const int t   = threadIdx.x;

  // ---- Phase A: blocks 0..31 bin partials ---------------------------------
  if (bid < 32) {
    const int set  = bid >> 4;
    const float* src  = (set == 0) ? det : rpn;
    const int    strd = (set == 0) ? 9 : 6;
    const int r = ((bid & 15) << 9) + t;

    if (t < 256) U.a.cnt[t] = 0u;
    __syncthreads();

    const float* p = src + (size_t)r * strd + 1;
    const float x1 = p[0], y1 = p[1], x2 = p[2], y2 = p[3];
    const float cxe = 0.5f * (x1 + x2), cye = 0.5f * (y1 + y2);
    const int ccx = min(15, max(0, (int)(cxe * (1.0f / 128.0f))));
    const int ccy = min(15, max(0, (int)(cye * (1.0f / 128.0f))));
    const unsigned cell = (unsigned)(ccy * 16 + ccx);        // local 0..255
    const unsigned rank = atomicAdd(&U.a.cnt[cell], 1u);     // LDS atomic
    __syncthreads();

    // wave0 shuffle-scan of 256 counts (4/lane) -> exclusive off[]
    if (t < 64) {
      const unsigned h0 = U.a.cnt[4 * t], h1 = U.a.cnt[4 * t + 1];
      const unsigned h2 = U.a.cnt[4 * t + 2], h3 = U.a.cnt[4 * t + 3];
      const unsigned lsum = h0 + h1 + h2 + h3;
      unsigned incl = lsum;
      #pragma unroll
      for (int d = 1; d < 64; d <<= 1) {
        const unsigned v = __shfl_up(incl, d);
        if (t >= d) incl += v;
      }
      const unsigned base = incl - lsum;
      U.a.off[4 * t] = base;                     U.a.off[4 * t + 1] = base + h0;
      U.a.off[4 * t + 2] = base + h0 + h1;       U.a.off[4 * t + 3] = base + h0 + h1 + h2;
    }
    __syncthreads();

    const unsigned pos = ((unsigned)bid << 9) + U.a.off[cell] + rank;
    astore(&pbw[pos * 4 + 0], __float_as_uint(x1));
    astore(&pbw[pos * 4 + 1], __float_as_uint(y1));
    astore(&pbw[pos * 4 + 2], __float_as_uint(x2));
    astore(&pbw[pos * 4 + 3], __float_as_uint(y2));
    astore(&pid[pos], (unsigned)r);
    if (t < 256) astore(&pofs[bid * 256 + t], U.a.off[t] | (U.a.cnt[t] << 16));

    asm volatile("s_waitcnt vmcnt(0)" ::: "memory");   // data at LLC
    if (t == 0) { astore(&fA[2 * bid], MG1); astore(&fA[2 * bid + 1], MG2); }
  }

  // ---- Join 1: everyone waits for the 32 binner flags ---------------------
  for (;;) {
    int ok = 1;
    if (t < 32)
      ok = (aload(&fA[2 * t]) == MG1) && (aload(&fA[2 * t + 1]) == MG2);
    if (__syncthreads_count(ok) == 512) break;
    __builtin_amdgcn_s_sleep(2);
  }

  // ---- Phase B: 2 pair tasks per block (det cell, then rpn cell) ----------
  for (int sub = 0; sub < 2; ++sub) {
    const int task = bid + (sub << 8);            // 0..511
    const int set = task >> 8, cellid = task & 255;
    const int cx = cellid & 15, cy = cellid >> 4;
    unsigned* myedges = edges + (size_t)task * RCAP;

    __syncthreads();                               // LDS reuse fence
    if (t == 0) {
      unsigned nN = 0;
      ncell[nN++] = (unsigned)cellid;              // CENTER FIRST (local id)
      for (int dy = -1; dy <= 1; ++dy)
        for (int dx = -1; dx <= 1; ++dx) {
          if (dx == 0 && dy == 0) continue;
          const int nx = cx + dx, ny = cy + dy;
          if (nx >= 0 && nx < 16 && ny >= 0 && ny < 16)
            ncell[nN++] = (unsigned)(ny * 16 + nx);
        }
      nN_sh = nN; eC = 0u; bad = 0u;
    }
    __syncthreads();
    const unsigned nN = nN_sh, nR = nN * 16;

    if (t < (int)nR) {
      const unsigned n = (unsigned)t >> 4, pp = (unsigned)t & 15u;
      const unsigned gpart = (unsigned)set * 16u + pp;
      const unsigned packed = aload(&pofs[gpart * 256u + ncell[n]]);
      U.p.runBase[t]  = (gpart << 9) + (packed & 0xFFFFu);
      U.p.runStart[t] = packed >> 16;              // count (prefixed below)
    }
    __syncthreads();
    if (t == 0) {
      unsigned acc = 0, na = 0;
      for (unsigned i = 0; i < nR; ++i) {
        const unsigned c = U.p.runStart[i];
        U.p.runStart[i] = acc;
        acc += c;
        if (i == 15) na = acc;                     // center = first 16 runs
      }
      na_sh = na; nb_sh = acc;
      if (acc > BCAP) bad = 1u;
    }
    __syncthreads();

    const unsigned na = na_sh, nb = nb_sh;
    const bool ok = (bad == 0u);                   // block-uniform

    if (ok) {
      // gather neighborhood entries via binary search over run starts
      for (unsigned idx = t; idx < nb; idx += 512) {
        unsigned lo = 0, hi = nR - 1;
        while (lo < hi) {
          const unsigned mid = (lo + hi + 1) >> 1;
          if (U.p.runStart[mid] <= idx) lo = mid; else hi = mid - 1;
        }
        const unsigned g = U.p.runBase[lo] + (idx - U.p.runStart[lo]);
        const float x1 = __uint_as_float(aload(&pbw[g * 4 + 0]));
        const float y1 = __uint_as_float(aload(&pbw[g * 4 + 1]));
        const float x2 = __uint_as_float(aload(&pbw[g * 4 + 2]));
        const float y2 = __uint_as_float(aload(&pbw[g * 4 + 3]));
        U.p.B4[idx]  = make_float4(x1, y1, x2, y2);
        U.p.Bar[idx] = fmaxf(x2 - x1, 0.0f) * fmaxf(y2 - y1, 0.0f); // ref
        U.p.Bid[idx] = aload(&pid[g]);
      }
    }
    __syncthreads();

    if (ok) {
      // flattened pair phase: a = center entries [0,na), b = all [0,nb)
      const unsigned tot = na * nb;
      for (unsigned pi = t; pi < tot; pi += 512) {
        const unsigned ai = pi / nb, x = pi - ai * nb;
        const unsigned ia = U.p.Bid[ai], ib = U.p.Bid[x];
        if (ia < ib) {                             // emit-once; skips self
          const float4 A = U.p.B4[ai], B = U.p.B4[x];
          const float ix1 = fmaxf(A.x, B.x), iy1 = fmaxf(A.y, B.y);
          const float ix2 = fminf(A.z, B.z), iy2 = fminf(A.w, B.w);
          const float inter = fmaxf(ix2 - ix1, 0.0f) * fmaxf(iy2 - iy1, 0.0f);
          if (inter > 0.0f) {
            const float uni = U.p.Bar[ai] + U.p.Bar[x] - inter; // ref order
            const float iou = inter / fmaxf(uni, 1e-9f);        // ref expr
            if (iou > IOU_T) {
              const unsigned slot = atomicAdd(&eC, 1u);         // LDS atomic
              if (slot < RCAP) astore(&myedges[slot], (ia << 13) | ib);
            }
          }
        }
      }
    } else {
      // exact fallback (never taken for this data): a = rows in this cell,
      // b = ALL rows; out-of-neighborhood pairs have inter==0 geometrically,
      // so semantics are identical to the fast path.
      const float* src  = (set == 0) ? det : rpn;
      const int    strd = (set == 0) ? 9 : 6;
      for (int ra = 0; ra < NROWS; ++ra) {
        const float* pa = src + (size_t)ra * strd + 1;
        const float ax1 = pa[0], ay1 = pa[1], ax2 = pa[2], ay2 = pa[3];
        const float cxe = 0.5f * (ax1 + ax2), cye = 0.5f * (ay1 + ay2);
        const int ccx = min(15, max(0, (int)(cxe * (1.0f / 128.0f))));
        const int ccy = min(15, max(0, (int)(cye * (1.0f / 128.0f))));
        if (ccx != cx || ccy != cy) continue;      // uniform skip
        const float aar = fmaxf(ax2 - ax1, 0.0f) * fmaxf(ay2 - ay1, 0.0f);
        for (int rb = t; rb < NROWS; rb += 512) {
          if ((unsigned)ra >= (unsigned)rb) continue;
          const float* pb = src + (size_t)rb * strd + 1;
          const float bx1 = pb[0], by1 = pb[1], bx2 = pb[2], by2 = pb[3];
          const float ix1 = fmaxf(ax1, bx1), iy1 = fmaxf(ay1, by1);
          const float ix2 = fminf(ax2, bx2), iy2 = fminf(ay2, by2);
          const float inter = fmaxf(ix2 - ix1, 0.0f) * fmaxf(iy2 - iy1, 0.0f);
          if (inter > 0.0f) {
            const float bar = fmaxf(bx2 - bx1, 0.0f) * fmaxf(by2 - by1, 0.0f);
            const float uni = aar + bar - inter;
            const float iou = inter / fmaxf(uni, 1e-9f);
            if (iou > IOU_T) {
              const unsigned slot = atomicAdd(&eC, 1u);
              if (slot < RCAP) astore(&myedges[slot], ((unsigned)ra << 13) | (unsigned)rb);
            }
          }
        }
      }
    }
    __syncthreads();
    if (t == 0) astore(&ecnt[task], min(eC, RCAP));
  }

  // ---- flag pair-done; non-solver blocks exit -----------------------------
  asm volatile("s_waitcnt vmcnt(0)" ::: "memory");   // edges+ecnt at LLC
  if (t == 0) { astore(&fB[2 * bid], MG1); astore(&fB[2 * bid + 1], MG2); }
  if (bid >= 32) return;

  // ---- Join 2: solver blocks wait for all 256 pair flags ------------------
  for (;;) {
    int ok = 1;
    if (t < 256)
      ok = (aload(&fB[2 * t]) == MG1) && (aload(&fB[2 * t + 1]) == MG2);
    if (__syncthreads_count(ok) == 512) break;
    __builtin_amdgcn_s_sleep(2);
  }

  // ---- Phase S: fixpoint + epilogue (set=bid>>4, slice=bid&15) ------------
  const int set = bid >> 4;
  const int slice = bid & 15;
  unsigned* gedges = edges + (size_t)set * 256 * RCAP;

  if (t < 256) U.s.rcnt[t] = min(aload(&ecnt[set * 256 + t]), RCAP);
  __syncthreads();

  // wave0 shuffle-scan of 256 region counts (4/lane)
  if (t < 64) {
    const unsigned h0 = U.s.rcnt[4 * t], h1 = U.s.rcnt[4 * t + 1];
    const unsigned h2 = U.s.rcnt[4 * t + 2], h3 = U.s.rcnt[4 * t + 3];
    const unsigned lsum = h0 + h1 + h2 + h3;
    unsigned incl = lsum;
    #pragma unroll
    for (int d = 1; d < 64; d <<= 1) {
      const unsigned v = __shfl_up(incl, d);
      if (t >= d) incl += v;
    }
    const unsigned base = incl - lsum;
    U.s.roff[4 * t] = base;               U.s.roff[4 * t + 1] = base + h0;
    U.s.roff[4 * t + 2] = base + h0 + h1; U.s.roff[4 * t + 3] = base + h0 + h1 + h2;
    if (t == 63) Etot_sh = incl;
  }
  if (t < NKW) U.s.kbuf[0][t] = 0xFFFFFFFFu;
  __syncthreads();

  const unsigned Etot = Etot_sh;
  const bool cached = (Etot <= ELDS);
  if (cached) {                 // gather: 2 threads per region (~6 loads ea)
    const unsigned rg = (unsigned)t >> 1, ln = (unsigned)t & 1u;
    const unsigned c = U.s.rcnt[rg], o = U.s.roff[rg];
    for (unsigned k = ln; k < c; k += 2u)
      U.s.eL[o + k] = aload(&gedges[(size_t)rg * RCAP + k]);
  }
  __syncthreads();

  int cur = 0;
  for (int round = 0; round < NROWS + 8; ++round) {
    const int nxt = cur ^ 1;
    if (t == 0) changed[round & 1] = 0;
    if (t < NKW) U.s.kbuf[nxt][t] = 0xFFFFFFFFu;
    __syncthreads();

    if (cached) {
      for (unsigned e = t; e < Etot; e += 512) {
        const unsigned pk = U.s.eL[e];
        const unsigned i = pk >> 13, j = pk & 8191u;
        if ((U.s.kbuf[cur][i >> 5] >> (i & 31)) & 1u)
          atomicAnd(&U.s.kbuf[nxt][j >> 5], ~(1u << (j & 31)));
      }
    } else {                    // exact slow path (never taken)
      for (unsigned r = (unsigned)t >> 1; r < 256u; r += 256u) {
        const unsigned c = U.s.rcnt[r];
        for (unsigned k = (unsigned)t & 1u; k < c; k += 2u) {
          const unsigned pk = aload(&gedges[(size_t)r * RCAP + k]);
          const unsigned i = pk >> 13, j = pk & 8191u;
          if ((U.s.kbuf[cur][i >> 5] >> (i & 31)) & 1u)
            atomicAnd(&U.s.kbuf[nxt][j >> 5], ~(1u << (j & 31)));
        }
      }
    }
    __syncthreads();

    if (t < NKW && U.s.kbuf[nxt][t] != U.s.kbuf[cur][t]) changed[round & 1] = 1;
    __syncthreads();

    cur = nxt;
    if (!changed[round & 1]) break;  // F(x)==x -> the unique fixpoint
  }

  // epilogue slice: 512 rows, coalesced float4 with magic-div row decode.
  const int r0 = slice * 512;
  if (set == 0) {
    {
      const int i = r0 + t;
      const bool kd = (U.s.kbuf[cur][i >> 5] >> (i & 31)) & 1u;
      const float* p = det + (size_t)i * 9;
      const float sc0 = p[5], sc1 = p[6], sc2 = p[7], sc3 = p[8];
      int am = 0; float best = sc0;
      if (sc1 > best) { best = sc1; am = 1; }   // first-max, like jnp.argmax
      if (sc2 > best) { best = sc2; am = 2; }
      if (sc3 > best) { best = sc3; am = 3; }
      U.s.vmsk[t] = (kd && am != 0) ? 1.0f : 0.0f;
      U.s.imsk[t] = (kd && am == 0) ? 1.0f : 0.0f;
    }
    __syncthreads();
    // slice = 512 rows x 9 dw = 4608 dw = 1152 float4, 16B-aligned bases
    const float4* in4 = reinterpret_cast<const float4*>(det + (size_t)r0 * 9);
    float4* o0 = reinterpret_cast<float4*>(out + (size_t)r0 * 9);
    float4* o1 = reinterpret_cast<float4*>(out + (size_t)NROWS * 9 + (size_t)r0 * 9);
    for (int q = t; q < 1152; q += 512) {
      const float4 v = in4[q];
      const float* vp = reinterpret_cast<const float*>(&v);
      float4 a, b;
      float* ap = reinterpret_cast<float*>(&a);
      float* bp = reinterpret_cast<float*>(&b);
      #pragma unroll
      for (int j = 0; j < 4; ++j) {
        const unsigned d = (unsigned)(q * 4 + j);
        const unsigned row = (d * 7282u) >> 16;        // == d/9 for d<4608
        ap[j] = vp[j] * U.s.vmsk[row];
        bp[j] = vp[j] * U.s.imsk[row];
      }
      o0[q] = a; o1[q] = b;
    }
  } else {
    {
      const int i = r0 + t;
      const bool kr = (U.s.kbuf[cur][i >> 5] >> (i & 31)) & 1u;
      U.s.vmsk[t] = kr ? 1.0f : 0.0f;
    }
    __syncthreads();
    // slice = 512 rows x 6 dw = 3072 dw = 768 float4, 16B-aligned bases
    const float4* in4 = reinterpret_cast<const float4*>(rpn + (size_t)r0 * 6);
    float4* o2 = reinterpret_cast<float4*>(out + (size_t)NROWS * 18 + (size_t)r0 * 6);
    for (int q = t; q < 768; q += 512) {
      const float4 v = in4[q];
      const float* vp = reinterpret_cast<const float*>(&v);
      float4 a;
      float* ap = reinterpret_cast<float*>(&a);
      #pragma unroll
      for (int j = 0; j < 4; ++j) {
        const unsigned d = (unsigned)(q * 4 + j);
        const unsigned row = (d * 10923u) >> 16;       // == d/6 for d<3072
        ap[j] = vp[j] * U.s.vmsk[row];
      }
      o2[q] = a;
    }
  }
}

// ---------------------------------------------------------------------------
extern "C" void kernel_launch(void* const* d_in, const int* in_sizes, int n_in,
                              void* d_out, int out_size, void* d_ws, size_t ws_size,
                              hipStream_t stream)
{
  const float* det = (const float*)d_in[0];   // 8192 x 9 fp32
  const float* rpn = (const float*)d_in[1];   // 8192 x 6 fp32
  float* out = (float*)d_out;                 // 8192*9 + 8192*9 + 8192*6 fp32

  char* ws = (char*)d_ws;
  unsigned* fA    = (unsigned*)(ws + OFF_FA);
  unsigned* fB    = (unsigned*)(ws + OFF_FB);
  unsigned* ecnt  = (unsigned*)(ws + OFF_ECNT);
  unsigned* edges = (unsigned*)(ws + OFF_EDGES);
  unsigned* pbw   = (unsigned*)(ws + OFF_PBW);
  unsigned* pid   = (unsigned*)(ws + OFF_PID);
  unsigned* pofs  = (unsigned*)(ws + OFF_POFS);

  fused2_kernel<<<256, 512, 0, stream>>>(det, rpn, fA, fB, ecnt, edges,
                                         pbw, pid, pofs, out);
}

// Round 6
// 75.422 us; speedup vs baseline: 1.1736x; 1.1736x over previous
//
#include <hip/hip_runtime.h>

// Pipeline_8400956031319: dual greedy NMS (8192 det + 8192 rpn, IOU>0.6,
// index order) + argmax masking.
//
// R17 rev — revert to the empirical best (R11, 75.5us) + one verified graft.
// Cross-round evidence (R11 75.5 / R13 79.5 / R15 78.2 / R16 88.5): totals
// are invariant to our-kernel work (full-scan ~30us vs binned ~12us) and to
// dispatch count (5 vs 2 vs 1); only SLOWER kernels move the total (up).
// => timed iteration ~= fill(40us @83% HBM, harness-fixed) + ~30-35us
// harness reset/replay overhead + max(0, kernel excess). The 75-80 band is
// the floor; R11's structure is its best-measured occupant. This round
// restores it exactly, with the R13-verified coalesced float4 epilogue
// (masks->LDS + magic-div row decode) grafted into solve_epi.
//
//   K1 scanpair (512 blocks x 512 thr, one block per (cell,set)):
//     scan all 8192 rows in 2 batches of 8 rows/thread — all 8 loads
//     issued before any use (8-deep MLP, 2 latency exposures vs 32);
//     stage 3x3 neighborhood of 128px cells in LDS (box <=120 < 128 =>
//     only 3x3 neighborhoods can overlap); flattened pair loop; exact ref
//     IOU; emit edges (i<<13|j, once via orig_a < orig_b) to a private
//     per-block region. No global atomics, no init kernel.
//   K2 solve_epi (32 blocks x 1024): gather set's ~3k edges to LDS
//     (4 threads per region => 3 serial loads, not 12), Jacobi fixpoint
//     keep[j] = !(exists i<j edge with keep[i]) (unique fixpoint == greedy
//     NMS; iterate until stable), then per-row masks to LDS and stream the
//     512-row output slice as contiguous float4 (magic-div row decode).

constexpr int NROWS = 8192;
constexpr int NKW   = 256;      // keep words (u32) per set
constexpr unsigned BCAP = 1536; // staged neighborhood cap (mean ~288)
constexpr unsigned ACAP = 512;  // cell-member cap (mean ~32)
constexpr unsigned RCAP = 2048; // per-block edge region cap (mean ~12)
constexpr unsigned ELDS = 16384;// solve LDS edge cache
#define IOU_T 0.6f

// ws layout: cnts[2][256] u32 @ 0 ; edges[2*256][RCAP] u32 @ 4096
constexpr size_t OFF_EDGES = 4096;

// ---------------------------------------------------------------------------
// K1: fused scan + pair. grid = (256 cells, 2 sets) x 512 threads.
// ---------------------------------------------------------------------------
__global__ __launch_bounds__(512) void scanpair_kernel(
    const float* __restrict__ det, const float* __restrict__ rpn,
    unsigned* __restrict__ cnts, unsigned* __restrict__ edges)
{
  const int cellid = blockIdx.x, set = blockIdx.y;
  const float* src  = (set == 0) ? det : rpn;
  const int    strd = (set == 0) ? 9 : 6;
  unsigned* myedges = edges + ((size_t)(set * 256 + cellid)) * RCAP;
  const int cx = cellid & 15, cy = cellid >> 4;

  __shared__ float Bx1[BCAP], By1[BCAP], Bx2[BCAP], By2[BCAP], Bar[BCAP];
  __shared__ unsigned Bid[BCAP];
  __shared__ unsigned aList[ACAP];
  __shared__ unsigned bCnt, aCnt, eCnt, ovf;

  const int t = threadIdx.x;
  if (t == 0) { bCnt = 0u; aCnt = 0u; eCnt = 0u; ovf = 0u; }
  __syncthreads();

  // scan: 16 rows/thread, 2 batches of 8. Loads for a whole batch are
  // issued before any consumption -> 8-deep MLP, 2 latency exposures.
  #pragma unroll
  for (int base = 0; base < 16; base += 8) {
    float rx1[8], ry1[8], rx2[8], ry2[8];
    #pragma unroll
    for (int k = 0; k < 8; ++k) {
      const int r = t + (base + k) * 512;
      const float* p = src + (size_t)r * strd + 1;
      rx1[k] = p[0]; ry1[k] = p[1]; rx2[k] = p[2]; ry2[k] = p[3];
    }
    #pragma unroll
    for (int k = 0; k < 8; ++k) {
      const int r = t + (base + k) * 512;
      const float x1 = rx1[k], y1 = ry1[k], x2 = rx2[k], y2 = ry2[k];
      const float cxe = 0.5f * (x1 + x2), cye = 0.5f * (y1 + y2);
      const int ccx = min(15, max(0, (int)(cxe * (1.0f / 128.0f))));
      const int ccy = min(15, max(0, (int)(cye * (1.0f / 128.0f))));
      const int dx = ccx - cx, dy = ccy - cy;
      if (dx >= -1 && dx <= 1 && dy >= -1 && dy <= 1) {
        const unsigned s = atomicAdd(&bCnt, 1u);
        if (s < BCAP) {
          Bx1[s] = x1; By1[s] = y1; Bx2[s] = x2; By2[s] = y2;
          Bar[s] = fmaxf(x2 - x1, 0.0f) * fmaxf(y2 - y1, 0.0f); // ref area
          Bid[s] = (unsigned)r;
          if (dx == 0 && dy == 0) {
            const unsigned as = atomicAdd(&aCnt, 1u);
            if (as < ACAP) aList[as] = s; else atomicOr(&ovf, 1u);
          }
        } else atomicOr(&ovf, 1u);
      }
    }
  }
  __syncthreads();

  const unsigned nb = min(bCnt, BCAP);
  const unsigned na = min(aCnt, ACAP);

  if (!ovf) {
    // flattened pair phase: all tests independent, LDS-resident
    const unsigned tot = na * nb;
    for (unsigned p = t; p < tot; p += 512) {
      const unsigned ai = p / nb, x = p - ai * nb;
      const unsigned s = aList[ai];
      const unsigned ia = Bid[s], ib = Bid[x];
      if (ia < ib) {                                   // emit-once; skips self
        const float ix1 = fmaxf(Bx1[s], Bx1[x]), iy1 = fmaxf(By1[s], By1[x]);
        const float ix2 = fminf(Bx2[s], Bx2[x]), iy2 = fminf(By2[s], By2[x]);
        const float inter = fmaxf(ix2 - ix1, 0.0f) * fmaxf(iy2 - iy1, 0.0f);
        if (inter > 0.0f) {
          const float uni = Bar[s] + Bar[x] - inter;          // ref order
          const float iou = inter / fmaxf(uni, 1e-9f);        // ref expr
          if (iou > IOU_T) {
            const unsigned slot = atomicAdd(&eCnt, 1u);       // LDS atomic
            if (slot < RCAP) myedges[slot] = (ia << 13) | ib;
          }
        }
      }
    }
  } else {
    // exact fallback (never taken for this data): a = rows in this cell,
    // b = ALL rows; out-of-neighborhood pairs have inter==0 geometrically,
    // so semantics are identical to the fast path.
    for (int ra = 0; ra < NROWS; ++ra) {
      const float* pa = src + (size_t)ra * strd + 1;
      const float ax1 = pa[0], ay1 = pa[1], ax2 = pa[2], ay2 = pa[3];
      const float cxe = 0.5f * (ax1 + ax2), cye = 0.5f * (ay1 + ay2);
      const int ccx = min(15, max(0, (int)(cxe * (1.0f / 128.0f))));
      const int ccy = min(15, max(0, (int)(cye * (1.0f / 128.0f))));
      if (ccx != cx || ccy != cy) continue;            // uniform skip
      const float aar = fmaxf(ax2 - ax1, 0.0f) * fmaxf(ay2 - ay1, 0.0f);
      for (int rb = t; rb < NROWS; rb += 512) {
        if ((unsigned)ra >= (unsigned)rb) continue;
        const float* pb = src + (size_t)rb * strd + 1;
        const float bx1 = pb[0], by1 = pb[1], bx2 = pb[2], by2 = pb[3];
        const float ix1 = fmaxf(ax1, bx1), iy1 = fmaxf(ay1, by1);
        const float ix2 = fminf(ax2, bx2), iy2 = fminf(ay2, by2);
        const float inter = fmaxf(ix2 - ix1, 0.0f) * fmaxf(iy2 - iy1, 0.0f);
        if (inter > 0.0f) {
          const float bar = fmaxf(bx2 - bx1, 0.0f) * fmaxf(by2 - by1, 0.0f);
          const float uni = aar + bar - inter;
          const float iou = inter / fmaxf(uni, 1e-9f);
          if (iou > IOU_T) {
            const unsigned slot = atomicAdd(&eCnt, 1u);
            if (slot < RCAP) myedges[slot] = ((unsigned)ra << 13) | (unsigned)rb;
          }
        }
      }
    }
  }
  __syncthreads();
  if (t == 0) cnts[set * 256 + cellid] = min(eCnt, RCAP);
}

// ---------------------------------------------------------------------------
// K2: fixpoint + epilogue. grid = 32 blocks x 1024. set = blk>>4; each block
// solves its set's fixpoint (redundantly, ~3k edges) then writes rows
// [slice*512, slice*512+512) of its outputs via coalesced float4 streaming.
// ---------------------------------------------------------------------------
__global__ __launch_bounds__(1024) void solve_epi_kernel(
    const float* __restrict__ det, const float* __restrict__ rpn,
    const unsigned* __restrict__ cnts, const unsigned* __restrict__ edges,
    float* __restrict__ out)
{
  const int blk = blockIdx.x;
  const int set = blk >> 4;
  const int slice = blk & 15;
  const unsigned* gedges = edges + (size_t)set * 256 * RCAP;

  __shared__ unsigned eL[ELDS];
  __shared__ unsigned rcnt[256], roff[256];
  __shared__ unsigned kbuf[2][NKW];
  __shared__ int changed[2];
  __shared__ unsigned Etot_sh;
  __shared__ float vmsk[512], imsk[512];   // per-row epilogue masks

  const int t = threadIdx.x;
  if (t < 256) rcnt[t] = min(cnts[set * 256 + t], RCAP);
  __syncthreads();

  // wave0 shuffle-scan of 256 region counts (4/lane)
  if (t < 64) {
    const unsigned h0 = rcnt[4 * t], h1 = rcnt[4 * t + 1];
    const unsigned h2 = rcnt[4 * t + 2], h3 = rcnt[4 * t + 3];
    const unsigned lsum = h0 + h1 + h2 + h3;
    unsigned incl = lsum;
    #pragma unroll
    for (int d = 1; d < 64; d <<= 1) {
      const unsigned v = __shfl_up(incl, d);
      if (t >= d) incl += v;
    }
    const unsigned base = incl - lsum;
    roff[4 * t] = base;               roff[4 * t + 1] = base + h0;
    roff[4 * t + 2] = base + h0 + h1; roff[4 * t + 3] = base + h0 + h1 + h2;
    if (t == 63) Etot_sh = incl;
  }
  if (t < NKW) kbuf[0][t] = 0xFFFFFFFFu;
  __syncthreads();

  const unsigned Etot = Etot_sh;
  const bool cached = (Etot <= ELDS);
  if (cached) {                 // gather: 4 threads per region (~3 loads ea)
    const unsigned rg = (unsigned)t >> 2, ln = (unsigned)t & 3u;
    const unsigned c = rcnt[rg], o = roff[rg];
    for (unsigned k = ln; k < c; k += 4u)
      eL[o + k] = gedges[(size_t)rg * RCAP + k];
  }
  __syncthreads();

  int cur = 0;
  for (int round = 0; round < NROWS + 8; ++round) {
    const int nxt = cur ^ 1;
    if (t == 0) changed[round & 1] = 0;
    if (t < NKW) kbuf[nxt][t] = 0xFFFFFFFFu;
    __syncthreads();

    if (cached) {
      for (unsigned e = t; e < Etot; e += 1024) {
        const unsigned pk = eL[e];
        const unsigned i = pk >> 13, j = pk & 8191u;
        if ((kbuf[cur][i >> 5] >> (i & 31)) & 1u)
          atomicAnd(&kbuf[nxt][j >> 5], ~(1u << (j & 31)));
      }
    } else {                    // exact slow path (never taken)
      for (unsigned r = (unsigned)t >> 2; r < 256u; r += 256u) {
        const unsigned c = rcnt[r];
        for (unsigned k = (unsigned)t & 3u; k < c; k += 4u) {
          const unsigned pk = gedges[(size_t)r * RCAP + k];
          const unsigned i = pk >> 13, j = pk & 8191u;
          if ((kbuf[cur][i >> 5] >> (i & 31)) & 1u)
            atomicAnd(&kbuf[nxt][j >> 5], ~(1u << (j & 31)));
        }
      }
    }
    __syncthreads();

    if (t < NKW && kbuf[nxt][t] != kbuf[cur][t]) changed[round & 1] = 1;
    __syncthreads();

    cur = nxt;
    if (!changed[round & 1]) break;  // F(x)==x -> the unique fixpoint
  }

  // epilogue slice: 512 rows per block, coalesced.
  // phase 1: per-row mask (0.0/1.0) into LDS; phase 2: stream contiguous
  // float4 with exact magic-div row decode (col stride 9 => d/9, 6 => d/6).
  const int r0 = slice * 512;
  if (set == 0) {
    if (t < 512) {
      const int i = r0 + t;
      const bool kd = (kbuf[cur][i >> 5] >> (i & 31)) & 1u;
      const float* p = det + (size_t)i * 9;
      const float sc0 = p[5], sc1 = p[6], sc2 = p[7], sc3 = p[8];
      int am = 0; float best = sc0;
      if (sc1 > best) { best = sc1; am = 1; }   // first-max, like jnp.argmax
      if (sc2 > best) { best = sc2; am = 2; }
      if (sc3 > best) { best = sc3; am = 3; }
      vmsk[t] = (kd && am != 0) ? 1.0f : 0.0f;
      imsk[t] = (kd && am == 0) ? 1.0f : 0.0f;
    }
    __syncthreads();
    // slice = 512 rows x 9 dw = 4608 dw = 1152 float4, 16B-aligned bases
    const float4* in4 = reinterpret_cast<const float4*>(det + (size_t)r0 * 9);
    float4* o0 = reinterpret_cast<float4*>(out + (size_t)r0 * 9);
    float4* o1 = reinterpret_cast<float4*>(out + (size_t)NROWS * 9 + (size_t)r0 * 9);
    for (int q = t; q < 1152; q += 1024) {
      const float4 v = in4[q];
      const float* vp = reinterpret_cast<const float*>(&v);
      float4 a, b;
      float* ap = reinterpret_cast<float*>(&a);
      float* bp = reinterpret_cast<float*>(&b);
      #pragma unroll
      for (int j = 0; j < 4; ++j) {
        const unsigned d = (unsigned)(q * 4 + j);
        const unsigned row = (d * 7282u) >> 16;        // == d/9 for d<4608
        ap[j] = vp[j] * vmsk[row];
        bp[j] = vp[j] * imsk[row];
      }
      o0[q] = a; o1[q] = b;
    }
  } else {
    if (t < 512) {
      const int i = r0 + t;
      const bool kr = (kbuf[cur][i >> 5] >> (i & 31)) & 1u;
      vmsk[t] = kr ? 1.0f : 0.0f;
    }
    __syncthreads();
    // slice = 512 rows x 6 dw = 3072 dw = 768 float4, 16B-aligned bases
    const float4* in4 = reinterpret_cast<const float4*>(rpn + (size_t)r0 * 6);
    float4* o2 = reinterpret_cast<float4*>(out + (size_t)NROWS * 18 + (size_t)r0 * 6);
    for (int q = t; q < 768; q += 1024) {
      const float4 v = in4[q];
      const float* vp = reinterpret_cast<const float*>(&v);
      float4 a;
      float* ap = reinterpret_cast<float*>(&a);
      #pragma unroll
      for (int j = 0; j < 4; ++j) {
        const unsigned d = (unsigned)(q * 4 + j);
        const unsigned row = (d * 10923u) >> 16;       // == d/6 for d<3072
        ap[j] = vp[j] * vmsk[row];
      }
      o2[q] = a;
    }
  }
}

// ---------------------------------------------------------------------------
extern "C" void kernel_launch(void* const* d_in, const int* in_sizes, int n_in,
                              void* d_out, int out_size, void* d_ws, size_t ws_size,
                              hipStream_t stream)
{
  const float* det = (const float*)d_in[0];   // 8192 x 9 fp32
  const float* rpn = (const float*)d_in[1];   // 8192 x 6 fp32
  float* out = (float*)d_out;                 // 8192*9 + 8192*9 + 8192*6 fp32

  char* ws = (char*)d_ws;
  unsigned* cnts  = (unsigned*)ws;            // [2][256] u32
  unsigned* edges = (unsigned*)(ws + OFF_EDGES);

  dim3 g1(256, 2);
  scanpair_kernel<<<g1, 512, 0, stream>>>(det, rpn, cnts, edges);
  solve_epi_kernel<<<32, 1024, 0, stream>>>(det, rpn, cnts, edges, out);
}